// Round 6
// baseline (501.285 us; speedup 1.0000x reference)
//
#include <hip/hip_runtime.h>
#include <hip/hip_bf16.h>

// Problem constants (from reference)
#define M_TOTAL 65536   // N_IDS
#define ND      128     // N_DOCS
#define FDIM    220     // FEATURE_DIM
#define KPAD    224     // FDIM padded to multiple of 32 for MFMA
#define HID     768     // HIDDEN
#define G8      28      // groups of 8 cols per 224-col padded row
#define BM      64      // M-tile rows per block
#define BSTRIDE 232     // LDS row stride (bf16): 464 B rows, 2-way conflict = free (m136)

using bf16_t = __hip_bfloat16;
using bf16x8 = __attribute__((ext_vector_type(8))) short;  // 8 bf16 = 4 VGPRs
using f32x4  = __attribute__((ext_vector_type(4))) float;  // native vec4 (MFMA acc + IO)

struct __align__(16) bf16v8 { bf16_t v[8]; };

__device__ __forceinline__ float slog(float x) {
  return copysignf(log1pf(fabsf(x)), x);  // log(|x|+1) * sign(x)
}

__device__ __forceinline__ f32x4 slog4(f32x4 f) {
  f32x4 y;
  y[0] = slog(f[0]); y[1] = slog(f[1]); y[2] = slog(f[2]); y[3] = slog(f[3]);
  return y;
}

__device__ __forceinline__ bf16x8 pack8(f32x4 a, f32x4 b) {
  bf16v8 h;
  h.v[0] = __float2bfloat16(a[0]); h.v[1] = __float2bfloat16(a[1]);
  h.v[2] = __float2bfloat16(a[2]); h.v[3] = __float2bfloat16(a[3]);
  h.v[4] = __float2bfloat16(b[0]); h.v[5] = __float2bfloat16(b[1]);
  h.v[6] = __float2bfloat16(b[2]); h.v[7] = __float2bfloat16(b[3]);
  return __builtin_bit_cast(bf16x8, h);
}

// ---------------------------------------------------------------------------
// Kernel 1 (tiny): W [768x220] fp32 -> Wb [768x224] bf16 in d_ws. 84 blocks.
// ---------------------------------------------------------------------------
__global__ __launch_bounds__(256) void convert_w_kernel(
    const float* __restrict__ W, bf16_t* __restrict__ Wb)
{
  const int j   = blockIdx.x * 256 + threadIdx.x;  // exact: 768*28 = 84*256
  const int row = j / G8;
  const int g   = j % G8;

  const float* src = W + (size_t)row * FDIM + g * 8;
  const f32x4 f0 = *(const f32x4*)src;            // cols 216..219 ok for g=27
  f32x4 f1;
  if (g < 27) f1 = *(const f32x4*)(src + 4);
  else        { f1[0] = 0.f; f1[1] = 0.f; f1[2] = 0.f; f1[3] = 0.f; }  // pad 220..223
  *(bf16v8*)(Wb + (size_t)row * KPAD + g * 8) = __builtin_bit_cast(bf16v8, pack8(f0, f1));
}

// ---------------------------------------------------------------------------
// Kernel 2 (fused): 64-row M-tile in LDS (29.7 KB), 4 blocks/CU resident so
//   the stage (gather-heavy) and GEMM (store-heavy) phases of different
//   blocks overlap — fixes R0's 2-block/CU phase convoying.
//   Waves split N (192 cols each), keeping per-wave tile 64x192:
//   MFMA:B-load = 4:1 (R4's 16-row waves were 1:1 -> L2-latency-bound).
//   MFMA operands SWAPPED: mfma(bg, af) — fragment layouts are symmetric so
//   loads are identical, but D's reg index walks out-COLS -> float4 stores
//   (4x fewer epilogue VMEM instructions than R0's scalar dwords).
// ---------------------------------------------------------------------------
__global__ __launch_bounds__(256, 4) void fused_gather_gemm_kernel(
    const int2* __restrict__ ids, const float* __restrict__ table,
    const bf16_t* __restrict__ Wb, const float* __restrict__ bias,
    float* __restrict__ out, float* __restrict__ fb)
{
  __shared__ bf16_t As[BM * BSTRIDE];  // 29696 B -> LDS allows 5, VGPR caps 4/CU

  const int tid   = threadIdx.x;
  const int bm    = blockIdx.x;  // 0..1023
  const int rbase = bm * BM;

  // ---- stage: 64 rows x 28 groups = 1792 tasks = 7 iters x 256 threads ----
#pragma unroll
  for (int it = 0; it < 7; ++it) {
    const int jj   = it * 256 + tid;
    const int row  = jj / G8;
    const int g    = jj % G8;
    const int grow = rbase + row;
    const int2 p   = ids[grow];
    const float* src = table + ((size_t)p.x * ND + p.y) * FDIM + g * 8;
    float*       dst = fb + (size_t)grow * FDIM + g * 8;

    const f32x4 y0 = slog4(*(const f32x4*)src);
    *(f32x4*)dst = y0;
    f32x4 y1;
    if (g < 27) {
      y1 = slog4(*(const f32x4*)(src + 4));
      *(f32x4*)(dst + 4) = y1;
    } else {
      y1[0] = 0.f; y1[1] = 0.f; y1[2] = 0.f; y1[3] = 0.f;  // pad cols 220..223
    }
    *(bf16v8*)(As + row * BSTRIDE + g * 8) = __builtin_bit_cast(bf16v8, pack8(y0, y1));
  }
  __syncthreads();  // the ONLY barrier

  const int wave = tid >> 6;
  const int lane = tid & 63;
  const int l15  = lane & 15;
  const int q    = lane >> 4;
  const int wn0  = wave * 192;   // this wave's 192-col N-slice

  // ---- GEMM: 3 N-tiles of 64 cols per wave ----
  for (int nt = 0; nt < 3; ++nt) {
    const int n0 = wn0 + nt * 64;
    f32x4 acc[4][4];
#pragma unroll
    for (int i = 0; i < 4; ++i)
#pragma unroll
      for (int j = 0; j < 4; ++j) acc[i][j] = (f32x4){0.f, 0.f, 0.f, 0.f};

    // bg as A-operand: lane (q,l15) holds Wb row (n0+ni*16+l15), cols kb*32+q*8
    const bf16_t* Wbase = Wb + (size_t)(n0 + l15) * KPAD + q * 8;

#pragma unroll
    for (int kb = 0; kb < 7; ++kb) {
      bf16x8 af[4];
#pragma unroll
      for (int mi = 0; mi < 4; ++mi)   // af as B-operand: row mi*16+l15, col kb*32+q*8
        af[mi] = *(const bf16x8*)(As + (mi * 16 + l15) * BSTRIDE + kb * 32 + q * 8);
      bf16x8 bg[4];
#pragma unroll
      for (int ni = 0; ni < 4; ++ni)
        bg[ni] = *(const bf16x8*)(Wbase + (size_t)(ni * 16) * KPAD + kb * 32);
#pragma unroll
      for (int mi = 0; mi < 4; ++mi)
#pragma unroll
        for (int ni = 0; ni < 4; ++ni)   // SWAPPED: A=bg (out-cols), B=af (out-rows)
          acc[mi][ni] = __builtin_amdgcn_mfma_f32_16x16x32_bf16(
              bg[ni], af[mi], acc[mi][ni], 0, 0, 0);
    }

    // epilogue: D col(lane&15) = out-row l15; D row(q*4+r) = out-col -> float4
#pragma unroll
    for (int ni = 0; ni < 4; ++ni) {
      const int ncol = n0 + ni * 16 + q * 4;
      f32x4 bv = *(const f32x4*)(bias + ncol);
#pragma unroll
      for (int mi = 0; mi < 4; ++mi) {
        f32x4 v = acc[mi][ni];
        v[0] += bv[0]; v[1] += bv[1]; v[2] += bv[2]; v[3] += bv[3];
        v[0] = v[0] > 0.f ? v[0] : 0.f;
        v[1] = v[1] > 0.f ? v[1] : 0.f;
        v[2] = v[2] > 0.f ? v[2] : 0.f;
        v[3] = v[3] > 0.f ? v[3] : 0.f;
        *(f32x4*)(out + (size_t)(rbase + mi * 16 + l15) * HID + ncol) = v;
      }
    }
  }
}

extern "C" void kernel_launch(void* const* d_in, const int* in_sizes, int n_in,
                              void* d_out, int out_size, void* d_ws, size_t ws_size,
                              hipStream_t stream) {
  (void)in_sizes; (void)n_in; (void)out_size; (void)ws_size;

  const int2*  ids   = (const int2*)d_in[0];
  const float* table = (const float*)d_in[1];
  const float* W     = (const float*)d_in[2];
  const float* bias  = (const float*)d_in[3];

  float* out_embeds = (float*)d_out;                          // 65536*768 fp32
  float* fb_f32     = (float*)d_out + (size_t)M_TOTAL * HID;  // 65536*220 fp32

  bf16_t* Wb = (bf16_t*)d_ws;  // 768*224 bf16 = 344 KB

  convert_w_kernel<<<(HID * G8) / 256, 256, 0, stream>>>(W, Wb);

  fused_gather_gemm_kernel<<<M_TOTAL / BM, 256, 0, stream>>>(
      ids, table, Wb, bias, out_embeds, fb_f32);
}